// Round 5
// baseline (265.267 us; speedup 1.0000x reference)
//
#include <hip/hip_runtime.h>

#define BB   16
#define FIN  16
#define FOUT 16
#define HH   384
#define WW   384
#define LAT  512
#define NMIX 8
#define HW   (HH * WW)          // 147456
#define HW4  (HW / 4)           // 36864 float4 per channel plane

typedef float f32x4 __attribute__((ext_vector_type(4)));

// ---------------------------------------------------------------------------
// r0 config (nt loads+stores, LDS weights, fused) with ONE structural change:
// NP=2 positions per thread, plane-major load issue.
//   - each wave delivers 2 back-to-back 1KB bursts per plane (was 1):
//     2x contiguous bytes per DRAM stream visit, 8KB/block/plane
//   - block count halves (1152): halves simultaneously-hot 4KB regions
//   - per-wave outstanding loads double to 32KB (offsets the occupancy
//     drop from 128 data VGPRs: ~3 waves/SIMD x 32KB > old 4-5 x 16KB)
// Theory: kernel runs 4.1 TB/s vs 6.3 copy ceiling because ~32K hot regions
// thrash DRAM row buffers; clustering bursts per stream raises row-hit rate.
// ---------------------------------------------------------------------------
__global__ __launch_bounds__(256)
void mixconv_fused(const float* __restrict__ x,
                   const float* __restrict__ lat,
                   const float* __restrict__ kernel_mix,   // [NMIX][FOUT][FIN]
                   const float* __restrict__ bias_mix,     // [NMIX][FOUT]
                   const float* __restrict__ w_dyn,        // [NMIX][LAT]
                   const float* __restrict__ b_dyn,        // [NMIX]
                   float* __restrict__ out) {
    __shared__ float part[NMIX][32];
    __shared__ float mix_s[NMIX];
    __shared__ float ksh[FOUT][FIN];
    __shared__ float bsh[FOUT];

    const int t = threadIdx.x;
    const int b = blockIdx.y;

    // ---- phase 0: issue x loads, plane-major pairs ------------------------
    // block covers 512 consecutive float4 per plane; thread t owns p and p+256
    const int p = blockIdx.x * 512 + t;
    const f32x4* xv = (const f32x4*)(x + (size_t)b * FIN * HW) + p;
    f32x4*       ov = (f32x4*)(out + (size_t)b * FOUT * HW) + p;

    f32x4 xa[FIN], xb[FIN];
#pragma unroll
    for (int i = 0; i < FIN; ++i) {
        xa[i] = __builtin_nontemporal_load(xv + (size_t)i * HW4);
        xb[i] = __builtin_nontemporal_load(xv + (size_t)i * HW4 + 256);
    }

    // ---- phase 1: mix[m] = lat[b] . w_dyn[m] + b_dyn[m] -------------------
    {
        const int m = t & (NMIX - 1);       // 0..7
        const int c = t >> 3;               // 0..31, chunk of 16 elements
        const f32x4* lv = (const f32x4*)(lat + (size_t)b * LAT + c * 16);
        const f32x4* wv = (const f32x4*)(w_dyn + (size_t)m * LAT + c * 16);
        float acc = 0.f;
#pragma unroll
        for (int j = 0; j < 4; ++j) {
            f32x4 a = lv[j], w = wv[j];
            acc += a.x * w.x + a.y * w.y + a.z * w.z + a.w * w.w;
        }
        part[m][c] = acc;
    }
    __syncthreads();
    if (t < NMIX) {
        float s = 0.f;
#pragma unroll
        for (int c = 0; c < 32; ++c) s += part[t][c];
        mix_s[t] = s + b_dyn[t];
    }
    __syncthreads();

    // ---- phase 2: fold per-sample weights into LDS -------------------------
    {
        float kacc = 0.f;
#pragma unroll
        for (int m = 0; m < NMIX; ++m)
            kacc += mix_s[m] * kernel_mix[m * FOUT * FIN + t];
        ((float*)ksh)[t] = kacc;
        if (t < FOUT) {
            float bacc = 0.f;
#pragma unroll
            for (int m = 0; m < NMIX; ++m)
                bacc += mix_s[m] * bias_mix[m * FOUT + t];
            bsh[t] = bacc;
        }
    }
    __syncthreads();

    // ---- phase 3: matvec on both positions, paired nt stores --------------
#pragma unroll
    for (int o = 0; o < FOUT; ++o) {
        const f32x4 k0 = *(const f32x4*)&ksh[o][0];
        const f32x4 k1 = *(const f32x4*)&ksh[o][4];
        const f32x4 k2 = *(const f32x4*)&ksh[o][8];
        const f32x4 k3 = *(const f32x4*)&ksh[o][12];
        const float bo = bsh[o];
        f32x4 aa = {bo, bo, bo, bo};
        f32x4 ab = aa;
        aa += k0.x * xa[0];  ab += k0.x * xb[0];
        aa += k0.y * xa[1];  ab += k0.y * xb[1];
        aa += k0.z * xa[2];  ab += k0.z * xb[2];
        aa += k0.w * xa[3];  ab += k0.w * xb[3];
        aa += k1.x * xa[4];  ab += k1.x * xb[4];
        aa += k1.y * xa[5];  ab += k1.y * xb[5];
        aa += k1.z * xa[6];  ab += k1.z * xb[6];
        aa += k1.w * xa[7];  ab += k1.w * xb[7];
        aa += k2.x * xa[8];  ab += k2.x * xb[8];
        aa += k2.y * xa[9];  ab += k2.y * xb[9];
        aa += k2.z * xa[10]; ab += k2.z * xb[10];
        aa += k2.w * xa[11]; ab += k2.w * xb[11];
        aa += k3.x * xa[12]; ab += k3.x * xb[12];
        aa += k3.y * xa[13]; ab += k3.y * xb[13];
        aa += k3.z * xa[14]; ab += k3.z * xb[14];
        aa += k3.w * xa[15]; ab += k3.w * xb[15];
        __builtin_nontemporal_store(aa, ov + (size_t)o * HW4);
        __builtin_nontemporal_store(ab, ov + (size_t)o * HW4 + 256);
    }
}

// ---------------------------------------------------------------------------
extern "C" void kernel_launch(void* const* d_in, const int* in_sizes, int n_in,
                              void* d_out, int out_size, void* d_ws, size_t ws_size,
                              hipStream_t stream) {
    const float* x          = (const float*)d_in[0];
    const float* lat        = (const float*)d_in[1];
    const float* kernel_mix = (const float*)d_in[2];
    const float* bias_mix   = (const float*)d_in[3];
    const float* w_dyn      = (const float*)d_in[4];
    const float* b_dyn      = (const float*)d_in[5];
    float* out = (float*)d_out;

    dim3 grid(HW4 / 512, BB);               // (72, 16) = 1152 blocks
    mixconv_fused<<<grid, dim3(256), 0, stream>>>(
        x, lat, kernel_mix, bias_mix, w_dyn, b_dyn, out);
}

// Round 6
// 255.898 us; speedup vs baseline: 1.0366x; 1.0366x over previous
//
#include <hip/hip_runtime.h>

#define BB   16
#define FIN  16
#define FOUT 16
#define HH   384
#define WW   384
#define LAT  512
#define NMIX 8
#define HW   (HH * WW)          // 147456
#define HW4  (HW / 4)           // 36864 float4 per channel plane

typedef float f32x4 __attribute__((ext_vector_type(4)));

// ---------------------------------------------------------------------------
// CHAMPION (r0 config, 254.8 us measured). Reverted after 5 single-variable
// probes (structure, cache policy both directions, weight path, occupancy
// both ways, burst clustering) all came back null or negative.
// Structural ceiling: every output position needs all 16 input planes at the
// same offset -> each wave's in-flight set is 16 read + 16 write streams at
// identical offsets mod the 576 KiB plane stride, irreducible without extra
// traffic. Memory system serves this geometry at ~4.1 TB/s -> ~74 us kernel;
// the remaining ~181 us of the timed figure is two fixed harness poison
// fills (~90 us each at 6.6-6.8 TB/s write-only).
// ---------------------------------------------------------------------------
__global__ __launch_bounds__(256)
void mixconv_fused(const float* __restrict__ x,
                   const float* __restrict__ lat,
                   const float* __restrict__ kernel_mix,   // [NMIX][FOUT][FIN]
                   const float* __restrict__ bias_mix,     // [NMIX][FOUT]
                   const float* __restrict__ w_dyn,        // [NMIX][LAT]
                   const float* __restrict__ b_dyn,        // [NMIX]
                   float* __restrict__ out) {
    __shared__ float part[NMIX][32];
    __shared__ float mix_s[NMIX];
    __shared__ float ksh[FOUT][FIN];
    __shared__ float bsh[FOUT];

    const int t = threadIdx.x;
    const int b = blockIdx.y;

    // ---- phase 0: issue streaming x loads first ---------------------------
    const int p = blockIdx.x * 256 + t;     // float4 index in [0, HW4)
    const f32x4* xv = (const f32x4*)(x + (size_t)b * FIN * HW) + p;
    f32x4*       ov = (f32x4*)(out + (size_t)b * FOUT * HW) + p;

    f32x4 xi[FIN];
#pragma unroll
    for (int i = 0; i < FIN; ++i)
        xi[i] = __builtin_nontemporal_load(xv + (size_t)i * HW4);

    // ---- phase 1: mix[m] = lat[b] . w_dyn[m] + b_dyn[m] -------------------
    {
        const int m = t & (NMIX - 1);       // 0..7
        const int c = t >> 3;               // 0..31, chunk of 16 elements
        const f32x4* lv = (const f32x4*)(lat + (size_t)b * LAT + c * 16);
        const f32x4* wv = (const f32x4*)(w_dyn + (size_t)m * LAT + c * 16);
        float acc = 0.f;
#pragma unroll
        for (int j = 0; j < 4; ++j) {
            f32x4 a = lv[j], w = wv[j];
            acc += a.x * w.x + a.y * w.y + a.z * w.z + a.w * w.w;
        }
        part[m][c] = acc;
    }
    __syncthreads();
    if (t < NMIX) {
        float s = 0.f;
#pragma unroll
        for (int c = 0; c < 32; ++c) s += part[t][c];
        mix_s[t] = s + b_dyn[t];
    }
    __syncthreads();

    // ---- phase 2: fold per-sample weights into LDS -------------------------
    {
        float kacc = 0.f;
#pragma unroll
        for (int m = 0; m < NMIX; ++m)
            kacc += mix_s[m] * kernel_mix[m * FOUT * FIN + t];
        ((float*)ksh)[t] = kacc;
        if (t < FOUT) {
            float bacc = 0.f;
#pragma unroll
            for (int m = 0; m < NMIX; ++m)
                bacc += mix_s[m] * bias_mix[m * FOUT + t];
            bsh[t] = bacc;
        }
    }
    __syncthreads();

    // ---- phase 3: consume x, matvec, stream out ---------------------------
#pragma unroll
    for (int o = 0; o < FOUT; ++o) {
        const f32x4 k0 = *(const f32x4*)&ksh[o][0];
        const f32x4 k1 = *(const f32x4*)&ksh[o][4];
        const f32x4 k2 = *(const f32x4*)&ksh[o][8];
        const f32x4 k3 = *(const f32x4*)&ksh[o][12];
        const float bo = bsh[o];
        f32x4 acc = {bo, bo, bo, bo};
        acc += k0.x * xi[0];  acc += k0.y * xi[1];
        acc += k0.z * xi[2];  acc += k0.w * xi[3];
        acc += k1.x * xi[4];  acc += k1.y * xi[5];
        acc += k1.z * xi[6];  acc += k1.w * xi[7];
        acc += k2.x * xi[8];  acc += k2.y * xi[9];
        acc += k2.z * xi[10]; acc += k2.w * xi[11];
        acc += k3.x * xi[12]; acc += k3.y * xi[13];
        acc += k3.z * xi[14]; acc += k3.w * xi[15];
        __builtin_nontemporal_store(acc, ov + (size_t)o * HW4);
    }
}

// ---------------------------------------------------------------------------
extern "C" void kernel_launch(void* const* d_in, const int* in_sizes, int n_in,
                              void* d_out, int out_size, void* d_ws, size_t ws_size,
                              hipStream_t stream) {
    const float* x          = (const float*)d_in[0];
    const float* lat        = (const float*)d_in[1];
    const float* kernel_mix = (const float*)d_in[2];
    const float* bias_mix   = (const float*)d_in[3];
    const float* w_dyn      = (const float*)d_in[4];
    const float* b_dyn      = (const float*)d_in[5];
    float* out = (float*)d_out;

    dim3 grid(HW4 / 256, BB);               // (144, 16) = 2304 blocks
    mixconv_fused<<<grid, dim3(256), 0, stream>>>(
        x, lat, kernel_mix, bias_mix, w_dyn, b_dyn, out);
}